// Round 1
// baseline (395.178 us; speedup 1.0000x reference)
//
#include <hip/hip_runtime.h>
#include <math.h>

typedef float f32x4 __attribute__((ext_vector_type(4)));
typedef __bf16 bf16x8 __attribute__((ext_vector_type(8)));
typedef __bf16 bf16x4 __attribute__((ext_vector_type(4)));

constexpr int Bc = 2, Tc = 2048, Dc = 768, Hc = 12, Kc = 64, Wc = 1024;
// scale * log2(e) so we can track raw-score max and use exp2
#define CEXP 0.18033688011112042f

__device__ __forceinline__ f32x4 mfma_bf16(bf16x8 a, bf16x8 b, f32x4 c) {
    return __builtin_amdgcn_mfma_f32_16x16x32_bf16(a, b, c, 0, 0, 0);
}

// ---------------- prep: fp32 weights -> bf16 transposed ----------------
// dst[n][k] = src[k][n]   (so B-operand fragments are contiguous along k)
__global__ __launch_bounds__(256) void k_prep_weights(
    const float* __restrict__ Wq, const float* __restrict__ Wk,
    const float* __restrict__ Wv, const float* __restrict__ Wgq,
    const float* __restrict__ Wo, const float* __restrict__ Wro,
    __bf16* __restrict__ dstbase)
{
    const float* srcs[6] = {Wq, Wk, Wv, Wgq, Wo, Wro};
    const float* src = srcs[blockIdx.y];
    __bf16* dst = dstbase + (size_t)blockIdx.y * Dc * Dc;
    int idx = blockIdx.x * 256 + threadIdx.x;   // 768*768 total
    int r = idx / Dc, c = idx - r * Dc;
    dst[(size_t)c * Dc + r] = (__bf16)src[idx];
}

// stateT[b,h][v][k] = state[b,h][k][v]
__global__ __launch_bounds__(256) void k_prep_state(
    const float* __restrict__ st, __bf16* __restrict__ stT)
{
    int idx = blockIdx.x * 256 + threadIdx.x;   // 24*64*64
    int bh = idx >> 12;
    int kk = (idx >> 6) & 63;
    int vv = idx & 63;
    stT[(size_t)bh * 4096 + vv * 64 + kk] = (__bf16)st[idx];
}

// ---------------- RMSNorm: x fp32 -> xn bf16 ----------------
__global__ __launch_bounds__(256) void k_rmsnorm(
    const float* __restrict__ x, const float* __restrict__ norm_w,
    __bf16* __restrict__ xnb)
{
    int row = blockIdx.x;          // 4096 rows
    int tid = threadIdx.x;
    const float* xr = x + (size_t)row * Dc;
    float4 v = make_float4(0.f, 0.f, 0.f, 0.f);
    float ss = 0.f;
    if (tid < 192) {
        v = ((const float4*)xr)[tid];
        ss = v.x * v.x + v.y * v.y + v.z * v.z + v.w * v.w;
    }
#pragma unroll
    for (int m = 32; m; m >>= 1) ss += __shfl_xor(ss, m, 64);
    __shared__ float red[4];
    if ((tid & 63) == 0) red[tid >> 6] = ss;
    __syncthreads();
    float tot = red[0] + red[1] + red[2] + red[3];
    float rms = rsqrtf(tot * (1.f / 768.f) + 1e-6f);
    if (tid < 192) {
        float4 nw = ((const float4*)norm_w)[tid];
        bf16x4 o;
        o[0] = (__bf16)(v.x * rms * nw.x);
        o[1] = (__bf16)(v.y * rms * nw.y);
        o[2] = (__bf16)(v.z * rms * nw.z);
        o[3] = (__bf16)(v.w * rms * nw.w);
        *(bf16x4*)(xnb + (size_t)row * Dc + tid * 4) = o;
    }
}

// ---------------- gate: gmean[b,t] = mean_h sigmoid(xn·Wg[:,h] + bg[h]) ----------------
__global__ __launch_bounds__(256) void k_gate(
    const __bf16* __restrict__ xnb, const float* __restrict__ Wg,
    const float* __restrict__ bg, float* __restrict__ gmean)
{
    int row = blockIdx.x * 4 + (threadIdx.x >> 6);   // one wave per row
    int lane = threadIdx.x & 63;
    const __bf16* xr = xnb + (size_t)row * Dc;
    float p[12];
#pragma unroll
    for (int h = 0; h < 12; ++h) p[h] = 0.f;
    for (int d = lane; d < Dc; d += 64) {
        float xv = (float)xr[d];
        const float* wr = Wg + d * 12;
#pragma unroll
        for (int h = 0; h < 12; ++h) p[h] += xv * wr[h];
    }
#pragma unroll
    for (int h = 0; h < 12; ++h) {
#pragma unroll
        for (int m = 32; m; m >>= 1) p[h] += __shfl_xor(p[h], m, 64);
    }
    if (lane == 0) {
        float s = 0.f;
#pragma unroll
        for (int h = 0; h < 12; ++h) s += 1.f / (1.f + expf(-(p[h] + bg[h])));
        gmean[row] = s * (1.f / 12.f);
    }
}

// ---------------- generic 64x64-tile MFMA GEMM: C = A(4096x768) @ BT(768x768)^T ----------------
// MODE 0: Cf fp32 row-major
// MODE 1: Cb bf16 scattered to (B,H,T,K)
// MODE 2: like 1 + relu
// MODE 3: Cb bf16 scattered to (B,H,K,T)   (v transposed)
// MODE 4: Cf = xres + Y1 + C  (fp32, final output)
template <int MODE>
__global__ __launch_bounds__(256) void k_gemm64(
    const __bf16* __restrict__ A, const __bf16* __restrict__ BT,
    float* __restrict__ Cf, __bf16* __restrict__ Cb,
    const float* __restrict__ xres, const float* __restrict__ Y1)
{
    int w = threadIdx.x >> 6, lane = threadIdx.x & 63;
    int g = lane >> 4, t = lane & 15;
    int m0 = blockIdx.x * 64 + w * 16;
    int n0 = blockIdx.y * 64;
    const __bf16* arow = A + (size_t)(m0 + t) * Dc;
    const __bf16* brow = BT + (size_t)(n0 + t) * Dc;
    f32x4 acc[4] = {};
    for (int k0 = 0; k0 < Dc; k0 += 32) {
        bf16x8 af = *(const bf16x8*)(arow + k0 + g * 8);
#pragma unroll
        for (int n = 0; n < 4; ++n) {
            bf16x8 bf = *(const bf16x8*)(brow + n * 16 * Dc + k0 + g * 8);
            acc[n] = mfma_bf16(af, bf, acc[n]);
        }
    }
#pragma unroll
    for (int n = 0; n < 4; ++n) {
#pragma unroll
        for (int r = 0; r < 4; ++r) {
            int row = m0 + g * 4 + r;
            int col = n0 + n * 16 + t;
            float v = acc[n][r];
            if (MODE == 0) {
                Cf[(size_t)row * Dc + col] = v;
            } else if (MODE == 1 || MODE == 2 || MODE == 3) {
                if (MODE == 2) v = fmaxf(v, 0.f);
                int b = row >> 11, ti = row & (Tc - 1);
                int h = col >> 6, kd = col & 63;
                if (MODE == 3)
                    Cb[((size_t)(b * Hc + h) * Kc + kd) * Tc + ti] = (__bf16)v;
                else
                    Cb[((size_t)(b * Hc + h) * Tc + ti) * Kc + kd] = (__bf16)v;
            } else {
                size_t idx = (size_t)row * Dc + col;
                Cf[idx] = xres[idx] + Y1[idx] + v;
            }
        }
    }
}

// ---------------- sliding-window flash attention ----------------
// grid (T/64, H, B), 4 waves; wave owns 16 q-rows; s-tiles of 32.
__global__ __launch_bounds__(256) void k_attn(
    const __bf16* __restrict__ q, const __bf16* __restrict__ k,
    const __bf16* __restrict__ vt, __bf16* __restrict__ localflat)
{
    int b = blockIdx.z, h = blockIdx.y;
    int w = threadIdx.x >> 6, lane = threadIdx.x & 63;
    int g = lane >> 4, t = lane & 15;
    int qw = blockIdx.x * 64 + w * 16;
    const __bf16* qb = q + (size_t)(b * Hc + h) * Tc * Kc;
    const __bf16* kb = k + (size_t)(b * Hc + h) * Tc * Kc;
    const __bf16* vb = vt + (size_t)(b * Hc + h) * Kc * Tc;

    bf16x8 qf0 = *(const bf16x8*)(qb + (size_t)(qw + t) * Kc + g * 8);
    bf16x8 qf1 = *(const bf16x8*)(qb + (size_t)(qw + t) * Kc + 32 + g * 8);

    f32x4 oacc[4] = {};
    float mrow[4] = {-INFINITY, -INFINITY, -INFINITY, -INFINITY};
    float lrow[4] = {0.f, 0.f, 0.f, 0.f};

    __shared__ __bf16 pld[4][16 * 32];   // per-wave private P tile
    __bf16* pw = pld[w];

    int s_begin = (qw > Wc) ? ((qw - Wc) & ~31) : 0;
    for (int s0 = s_begin; s0 <= qw + 15; s0 += 32) {
        // scores: S[16q x 32s] as two 16-col subtiles
        f32x4 sc0 = {}, sc1 = {};
        {
            const __bf16* kr = kb + (size_t)(s0 + t) * Kc + g * 8;
            sc0 = mfma_bf16(qf0, *(const bf16x8*)kr, sc0);
            sc0 = mfma_bf16(qf1, *(const bf16x8*)(kr + 32), sc0);
        }
        {
            const __bf16* kr = kb + (size_t)(s0 + 16 + t) * Kc + g * 8;
            sc1 = mfma_bf16(qf0, *(const bf16x8*)kr, sc1);
            sc1 = mfma_bf16(qf1, *(const bf16x8*)(kr + 32), sc1);
        }
        float fac[4], p0v[4], p1v[4];
#pragma unroll
        for (int r = 0; r < 4; ++r) {
            int qi = qw + g * 4 + r;
            int sA = s0 + t, sB = s0 + 16 + t;
            bool a0 = (sA <= qi) && (sA >= qi - Wc);
            bool a1 = (sB <= qi) && (sB >= qi - Wc);
            float x0 = a0 ? sc0[r] : -INFINITY;
            float x1 = a1 ? sc1[r] : -INFINITY;
            float tmax = fmaxf(x0, x1);
#pragma unroll
            for (int msk = 8; msk; msk >>= 1) tmax = fmaxf(tmax, __shfl_xor(tmax, msk, 16));
            float mnew = fmaxf(mrow[r], tmax);
            float f = (mnew == -INFINITY) ? 1.f : exp2f((mrow[r] - mnew) * CEXP);
            float p0 = a0 ? exp2f((sc0[r] - mnew) * CEXP) : 0.f;
            float p1 = a1 ? exp2f((sc1[r] - mnew) * CEXP) : 0.f;
            float rs = p0 + p1;
#pragma unroll
            for (int msk = 8; msk; msk >>= 1) rs += __shfl_xor(rs, msk, 16);
            lrow[r] = lrow[r] * f + rs;
            mrow[r] = mnew;
            fac[r] = f; p0v[r] = p0; p1v[r] = p1;
        }
#pragma unroll
        for (int n = 0; n < 4; ++n) {
            oacc[n][0] *= fac[0]; oacc[n][1] *= fac[1];
            oacc[n][2] *= fac[2]; oacc[n][3] *= fac[3];
        }
        // P (16x32) through wave-private LDS to get A-operand layout
#pragma unroll
        for (int r = 0; r < 4; ++r) {
            pw[(g * 4 + r) * 32 + t]      = (__bf16)p0v[r];
            pw[(g * 4 + r) * 32 + 16 + t] = (__bf16)p1v[r];
        }
        asm volatile("s_waitcnt lgkmcnt(0)" ::: "memory");
        bf16x8 pf = *(const bf16x8*)(pw + t * 32 + g * 8);
#pragma unroll
        for (int n = 0; n < 4; ++n) {
            const __bf16* vr = vb + (size_t)(n * 16 + t) * Tc + s0 + g * 8;
            oacc[n] = mfma_bf16(pf, *(const bf16x8*)vr, oacc[n]);
        }
    }
    float inv[4];
#pragma unroll
    for (int r = 0; r < 4; ++r) inv[r] = 1.f / lrow[r];
#pragma unroll
    for (int n = 0; n < 4; ++n) {
#pragma unroll
        for (int r = 0; r < 4; ++r) {
            int qi = qw + g * 4 + r;
            localflat[(size_t)(b * Tc + qi) * Dc + h * 64 + n * 16 + t] =
                (__bf16)(oacc[n][r] * inv[r]);
        }
    }
}

// ---------------- GDN retrieval: retr[b,t, h*64+v] = gmean * sum_k qg*stateT ----------------
__global__ __launch_bounds__(256) void k_retr(
    const __bf16* __restrict__ qg, const __bf16* __restrict__ stateT,
    const float* __restrict__ gmean, __bf16* __restrict__ retrflat)
{
    int b = blockIdx.z, h = blockIdx.y;
    int w = threadIdx.x >> 6, lane = threadIdx.x & 63;
    int g = lane >> 4, t = lane & 15;
    int t0 = blockIdx.x * 64 + w * 16;
    const __bf16* qb = qg + (size_t)(b * Hc + h) * Tc * Kc;
    const __bf16* sb = stateT + (size_t)(b * Hc + h) * Kc * Kc;
    bf16x8 a0 = *(const bf16x8*)(qb + (size_t)(t0 + t) * Kc + g * 8);
    bf16x8 a1 = *(const bf16x8*)(qb + (size_t)(t0 + t) * Kc + 32 + g * 8);
#pragma unroll
    for (int n = 0; n < 4; ++n) {
        bf16x8 b0 = *(const bf16x8*)(sb + (n * 16 + t) * Kc + g * 8);
        bf16x8 b1 = *(const bf16x8*)(sb + (n * 16 + t) * Kc + 32 + g * 8);
        f32x4 acc = {};
        acc = mfma_bf16(a0, b0, acc);
        acc = mfma_bf16(a1, b1, acc);
#pragma unroll
        for (int r = 0; r < 4; ++r) {
            int ti = t0 + g * 4 + r;
            float gm = gmean[b * Tc + ti];
            retrflat[(size_t)(b * Tc + ti) * Dc + h * 64 + n * 16 + t] =
                (__bf16)(acc[r] * gm);
        }
    }
}

// ---------------- host ----------------
extern "C" void kernel_launch(void* const* d_in, const int* in_sizes, int n_in,
                              void* d_out, int out_size, void* d_ws, size_t ws_size,
                              hipStream_t stream) {
    (void)in_sizes; (void)n_in; (void)out_size; (void)ws_size;
    const float* x     = (const float*)d_in[0];
    const float* gdn   = (const float*)d_in[1];
    const float* Wq    = (const float*)d_in[2];
    const float* Wk    = (const float*)d_in[3];
    const float* Wv    = (const float*)d_in[4];
    const float* Wo    = (const float*)d_in[5];
    const float* Wgq   = (const float*)d_in[6];
    const float* Wro   = (const float*)d_in[7];
    const float* Wg    = (const float*)d_in[8];
    const float* bg    = (const float*)d_in[9];
    const float* normw = (const float*)d_in[10];
    float* out = (float*)d_out;

    char* p = (char*)d_ws;
    auto alloc = [&](size_t bytes) -> char* {
        char* r = p; p += (bytes + 255) & ~(size_t)255; return r;
    };
    constexpr size_t NROW = (size_t)Bc * Tc;          // 4096
    constexpr size_t W2   = (size_t)Dc * Dc;          // 589824
    __bf16* xnb    = (__bf16*)alloc(NROW * Dc * 2);
    __bf16* wT     = (__bf16*)alloc(6 * W2 * 2);
    __bf16* stT    = (__bf16*)alloc((size_t)Bc * Hc * Kc * Kc * 2);
    __bf16* qbuf   = (__bf16*)alloc(NROW * Dc * 2);
    __bf16* kbuf   = (__bf16*)alloc(NROW * Dc * 2);
    __bf16* qgbuf  = (__bf16*)alloc(NROW * Dc * 2);
    __bf16* vtbuf  = (__bf16*)alloc(NROW * Dc * 2);
    __bf16* localf = (__bf16*)alloc(NROW * Dc * 2);
    __bf16* retrf  = (__bf16*)alloc(NROW * Dc * 2);
    float*  Y1     = (float*)alloc(NROW * Dc * 4);
    float*  gmean  = (float*)alloc(NROW * 4);

    k_prep_weights<<<dim3(W2 / 256, 6), 256, 0, stream>>>(Wq, Wk, Wv, Wgq, Wo, Wro, wT);
    k_prep_state<<<(Bc * Hc * Kc * Kc) / 256, 256, 0, stream>>>(gdn, stT);
    k_rmsnorm<<<NROW, 256, 0, stream>>>(x, normw, xnb);
    k_gate<<<NROW / 4, 256, 0, stream>>>(xnb, Wg, bg, gmean);

    dim3 gg(NROW / 64, Dc / 64);
    k_gemm64<1><<<gg, 256, 0, stream>>>(xnb, wT + 0 * W2, nullptr, qbuf,  nullptr, nullptr);
    k_gemm64<1><<<gg, 256, 0, stream>>>(xnb, wT + 1 * W2, nullptr, kbuf,  nullptr, nullptr);
    k_gemm64<3><<<gg, 256, 0, stream>>>(xnb, wT + 2 * W2, nullptr, vtbuf, nullptr, nullptr);
    k_gemm64<2><<<gg, 256, 0, stream>>>(xnb, wT + 3 * W2, nullptr, qgbuf, nullptr, nullptr);

    k_attn<<<dim3(Tc / 64, Hc, Bc), 256, 0, stream>>>(qbuf, kbuf, vtbuf, localf);
    k_retr<<<dim3(Tc / 64, Hc, Bc), 256, 0, stream>>>(qgbuf, stT, gmean, retrf);

    k_gemm64<0><<<gg, 256, 0, stream>>>(localf, wT + 4 * W2, Y1, nullptr, nullptr, nullptr);
    k_gemm64<4><<<gg, 256, 0, stream>>>(retrf,  wT + 5 * W2, out, nullptr, x, Y1);
}

// Round 2
// 193.671 us; speedup vs baseline: 2.0405x; 2.0405x over previous
//
#include <hip/hip_runtime.h>
#include <math.h>
#include <stdint.h>

typedef float f32x4 __attribute__((ext_vector_type(4)));
typedef __bf16 bf16x8 __attribute__((ext_vector_type(8)));
typedef __bf16 bf16x4 __attribute__((ext_vector_type(4)));

constexpr int Bc = 2, Tc = 2048, Dc = 768, Hc = 12, Kc = 64, Wc = 1024;
// 1/sqrt(64) * log2(e), folded into Wq at prep time
#define CEXP 0.18033688011112042f

__device__ __forceinline__ f32x4 mfma_bf16(bf16x8 a, bf16x8 b, f32x4 c) {
    return __builtin_amdgcn_mfma_f32_16x16x32_bf16(a, b, c, 0, 0, 0);
}
__device__ __forceinline__ void gload16(const void* g, void* l) {
    __builtin_amdgcn_global_load_lds(
        (const __attribute__((address_space(1))) uint32_t*)g,
        (__attribute__((address_space(3))) uint32_t*)l, 16, 0, 0);
}
__device__ __forceinline__ uint32_t pack2(float a, float b) {
    union { __bf16 h[2]; uint32_t u; } x;
    x.h[0] = (__bf16)a; x.h[1] = (__bf16)b; return x.u;
}

// ---------------- weight transpose prep (LDS-tiled) ----------------
// wsel 0..3: Wq,Wk,Wv,Wgq -> wTproj rows wsel*768.. ; wsel 4: Wo -> wTout k 0..767;
// wsel 5: Wro -> wTout k 768..1535.  dst[n][k] = src[k][n].  Wq scaled by CEXP.
__global__ __launch_bounds__(256) void k_prep_w(
    const float* __restrict__ Wq, const float* __restrict__ Wk,
    const float* __restrict__ Wv, const float* __restrict__ Wgq,
    const float* __restrict__ Wo, const float* __restrict__ Wro,
    __bf16* __restrict__ wTproj, __bf16* __restrict__ wTout)
{
    __shared__ __bf16 ldsT[64][66];
    const int wsel = blockIdx.y;
    const float* srcs[6] = {Wq, Wk, Wv, Wgq, Wo, Wro};
    const float* src = srcs[wsel];
    __bf16* dst; int dstride, koff;
    if (wsel < 4) { dst = wTproj + (size_t)wsel * Dc * Dc; dstride = Dc;  koff = 0; }
    else if (wsel == 4) { dst = wTout; dstride = 1536; koff = 0; }
    else { dst = wTout; dstride = 1536; koff = 768; }
    const float scale = (wsel == 0) ? CEXP : 1.0f;

    int tile = blockIdx.x;              // 144 = 12x12 tiles of 64x64
    int tk = tile % 12, tn = tile / 12;
    int k0 = tk * 64, n0 = tn * 64;
    int i = threadIdx.x, rsub = i >> 4, c4 = i & 15;
#pragma unroll
    for (int rep = 0; rep < 4; ++rep) {
        int row = rep * 16 + rsub;      // k-local
        float4 v = *(const float4*)(src + (size_t)(k0 + row) * Dc + n0 + c4 * 4);
        ldsT[c4 * 4 + 0][row] = (__bf16)(v.x * scale);
        ldsT[c4 * 4 + 1][row] = (__bf16)(v.y * scale);
        ldsT[c4 * 4 + 2][row] = (__bf16)(v.z * scale);
        ldsT[c4 * 4 + 3][row] = (__bf16)(v.w * scale);
    }
    __syncthreads();
#pragma unroll
    for (int rep = 0; rep < 4; ++rep) {
        int n = rep * 16 + rsub;        // n-local
        bf16x4 o = *(const bf16x4*)&ldsT[n][c4 * 4];
        *(bf16x4*)(dst + (size_t)(n0 + n) * dstride + koff + k0 + c4 * 4) = o;
    }
}

// stateT[b,h][v][k] = state[b,h][k][v]
__global__ __launch_bounds__(256) void k_prep_state(
    const float* __restrict__ st, __bf16* __restrict__ stT)
{
    int idx = blockIdx.x * 256 + threadIdx.x;   // 24*64*64
    int bh = idx >> 12, kk = (idx >> 6) & 63, vv = idx & 63;
    stT[(size_t)bh * 4096 + vv * 64 + kk] = (__bf16)st[idx];
}

// ---------------- RMSNorm: x fp32 -> xn bf16 ----------------
__global__ __launch_bounds__(256) void k_rmsnorm(
    const float* __restrict__ x, const float* __restrict__ norm_w,
    __bf16* __restrict__ xnb)
{
    int row = blockIdx.x, tid = threadIdx.x;
    const float* xr = x + (size_t)row * Dc;
    float4 v = make_float4(0.f, 0.f, 0.f, 0.f);
    float ss = 0.f;
    if (tid < 192) {
        v = ((const float4*)xr)[tid];
        ss = v.x * v.x + v.y * v.y + v.z * v.z + v.w * v.w;
    }
#pragma unroll
    for (int m = 32; m; m >>= 1) ss += __shfl_xor(ss, m, 64);
    __shared__ float red[4];
    if ((tid & 63) == 0) red[tid >> 6] = ss;
    __syncthreads();
    float tot = red[0] + red[1] + red[2] + red[3];
    float rms = rsqrtf(tot * (1.f / 768.f) + 1e-6f);
    if (tid < 192) {
        float4 nw = ((const float4*)norm_w)[tid];
        bf16x4 o;
        o[0] = (__bf16)(v.x * rms * nw.x);
        o[1] = (__bf16)(v.y * rms * nw.y);
        o[2] = (__bf16)(v.z * rms * nw.z);
        o[3] = (__bf16)(v.w * rms * nw.w);
        *(bf16x4*)(xnb + (size_t)row * Dc + tid * 4) = o;
    }
}

// ---------------- gate: gmean[b,t] = mean_h sigmoid(xn·Wg[:,h] + bg[h]) ----------------
__global__ __launch_bounds__(256) void k_gate(
    const __bf16* __restrict__ xnb, const float* __restrict__ Wg,
    const float* __restrict__ bg, float* __restrict__ gmean)
{
    int row = blockIdx.x * 4 + (threadIdx.x >> 6);
    int lane = threadIdx.x & 63;
    const __bf16* xr = xnb + (size_t)row * Dc;
    float p[12];
#pragma unroll
    for (int h = 0; h < 12; ++h) p[h] = 0.f;
    for (int d = lane; d < Dc; d += 64) {
        float xv = (float)xr[d];
        const float* wr = Wg + d * 12;
#pragma unroll
        for (int h = 0; h < 12; ++h) p[h] += xv * wr[h];
    }
#pragma unroll
    for (int h = 0; h < 12; ++h) {
#pragma unroll
        for (int m = 32; m; m >>= 1) p[h] += __shfl_xor(p[h], m, 64);
    }
    if (lane == 0) {
        float s = 0.f;
#pragma unroll
        for (int h = 0; h < 12; ++h) s += 1.f / (1.f + expf(-(p[h] + bg[h])));
        gmean[row] = s * (1.f / 12.f);
    }
}

// ---------------- m97-style LDS-staged GEMM ----------------
// MODE 0: A=xn(4096x768), BT=wTproj(3072x768); epilogue scatters q/k/v/qg
// MODE 1: A=ac(4096x1536), BT=wTout(768x1536);  out = x + A@BT^T (fp32)
template <int MODE>
__global__ __launch_bounds__(256) void k_gemm(
    const __bf16* __restrict__ A, const __bf16* __restrict__ BT,
    const float* __restrict__ xres, float* __restrict__ outf,
    __bf16* __restrict__ qb, __bf16* __restrict__ kbf,
    __bf16* __restrict__ vtb, __bf16* __restrict__ qgb)
{
    constexpr int BM = (MODE == 0) ? 128 : 64;
    constexpr int KD = (MODE == 0) ? 768 : 1536;
    constexpr int NC = (MODE == 0) ? 4 : 2;
    __shared__ __bf16 As[BM * 32];
    __shared__ __bf16 Bs[128 * 32];
    const int tid = threadIdx.x, w = tid >> 6, lane = tid & 63;
    const int g = lane >> 4, t = lane & 15;
    int m0, n0;
    {
        int id = blockIdx.x, xcd = id & 7, l = id >> 3;
        if (MODE == 0) { m0 = ((l & 7) | ((xcd & 3) << 3)) * 128; n0 = ((l >> 3) + (xcd >> 2) * 12) * 128; }
        else           { m0 = ((xcd << 3) | (l & 7)) * 64;        n0 = (l >> 3) * 128; }
    }
    const __bf16* Abase = A + (size_t)m0 * KD;
    const __bf16* Bbase = BT + (size_t)n0 * KD;
    const int wrow = (MODE == 0) ? (w >> 1) * 64 : 0;
    const int wcol = (MODE == 0) ? (w & 1) * 64 : w * 32;

    f32x4 acc[4][NC] = {};
    for (int k0 = 0; k0 < KD; k0 += 32) {
#pragma unroll
        for (int c = 0; c < BM / 64; ++c) {
            int chunk = c * 256 + tid, row = chunk >> 2, cix = chunk & 3;
            gload16(Abase + (size_t)row * KD + k0 + cix * 8, As + chunk * 8);
        }
#pragma unroll
        for (int c = 0; c < 2; ++c) {
            int chunk = c * 256 + tid, row = chunk >> 2, cix = chunk & 3;
            gload16(Bbase + (size_t)row * KD + k0 + cix * 8, Bs + chunk * 8);
        }
        __syncthreads();
        bf16x8 af[4], bfr[NC];
#pragma unroll
        for (int mi = 0; mi < 4; ++mi)
            af[mi] = *(const bf16x8*)(As + (wrow + mi * 16 + t) * 32 + g * 8);
#pragma unroll
        for (int ni = 0; ni < NC; ++ni)
            bfr[ni] = *(const bf16x8*)(Bs + (wcol + ni * 16 + t) * 32 + g * 8);
#pragma unroll
        for (int mi = 0; mi < 4; ++mi)
#pragma unroll
            for (int ni = 0; ni < NC; ++ni)
                acc[mi][ni] = mfma_bf16(af[mi], bfr[ni], acc[mi][ni]);
        __syncthreads();
    }
    const int region = (MODE == 0) ? (n0 / 768) : 0;
#pragma unroll
    for (int mi = 0; mi < 4; ++mi)
#pragma unroll
        for (int ni = 0; ni < NC; ++ni)
#pragma unroll
            for (int r = 0; r < 4; ++r) {
                int grow = m0 + wrow + mi * 16 + g * 4 + r;
                int gcol = n0 + wcol + ni * 16 + t;
                float v = acc[mi][ni][r];
                if (MODE == 1) {
                    size_t idx = (size_t)grow * Dc + gcol;
                    outf[idx] = xres[idx] + v;
                } else {
                    int c = gcol - region * 768;
                    int h = c >> 6, kd = c & 63;
                    int b = grow >> 11, ti = grow & (Tc - 1);
                    if (region == 0)
                        qb[((size_t)(b * Hc + h) * Tc + ti) * 64 + kd] = (__bf16)v;
                    else if (region == 1)
                        kbf[((size_t)(b * Hc + h) * Tc + ti) * 64 + kd] = (__bf16)v;
                    else if (region == 2) {
                        // key-pair permutation so attention's packed-P pairs line up
                        int ts = (ti & ~31) | ((ti & 15) << 1) | ((ti >> 4) & 1);
                        vtb[((size_t)(b * Hc + h) * 64 + kd) * Tc + ts] = (__bf16)v;
                    } else
                        qgb[((size_t)(b * Hc + h) * Tc + ti) * 64 + kd] = (__bf16)fmaxf(v, 0.f);
                }
            }
}

// ---------------- sliding-window attention, fixed-max softmax ----------------
// grid: 768 flattened (XCD-swizzled); 4 waves, wave = 16 q-rows, 32-key steps.
__global__ __launch_bounds__(256) void k_attn(
    const __bf16* __restrict__ q, const __bf16* __restrict__ k,
    const __bf16* __restrict__ vt, __bf16* __restrict__ ac)
{
    int id = blockIdx.x, xcd = id & 7, l = id >> 3;
    int nid = xcd * 96 + l;                 // contiguous chunk per XCD
    int sblk = nid & 31, h = (nid >> 5) % Hc, b = nid / (32 * Hc);
    int w = threadIdx.x >> 6, lane = threadIdx.x & 63;
    int g = lane >> 4, t = lane & 15;
    int qw = sblk * 64 + w * 16;
    const __bf16* qb = q + (size_t)(b * Hc + h) * Tc * 64;
    const __bf16* kb = k + (size_t)(b * Hc + h) * Tc * 64;
    const __bf16* vb = vt + (size_t)(b * Hc + h) * 64 * Tc;

    bf16x8 qf0 = *(const bf16x8*)(qb + (size_t)(qw + t) * 64 + g * 8);
    bf16x8 qf1 = *(const bf16x8*)(qb + (size_t)(qw + t) * 64 + 32 + g * 8);

    f32x4 oacc[4] = {};
    float lrow[4] = {0.f, 0.f, 0.f, 0.f};
    __shared__ uint32_t pld[4][16 * 16];    // per-wave P tile, packed pairs
    uint32_t* pw = pld[w];

    int s_begin = (qw > Wc) ? ((qw - Wc) & ~31) : 0;
    int s_end = qw + 15;
    for (int s0 = s_begin; s0 <= s_end; s0 += 32) {
        f32x4 sc0 = {}, sc1 = {};
        {
            const __bf16* kr = kb + (size_t)(s0 + t) * 64 + g * 8;
            sc0 = mfma_bf16(qf0, *(const bf16x8*)kr, sc0);
            sc0 = mfma_bf16(qf1, *(const bf16x8*)(kr + 32), sc0);
            const __bf16* kr2 = kr + 16 * 64;
            sc1 = mfma_bf16(qf0, *(const bf16x8*)kr2, sc1);
            sc1 = mfma_bf16(qf1, *(const bf16x8*)(kr2 + 32), sc1);
        }
        float p0[4], p1[4];
        bool full = (s0 + 31 <= qw) && (s0 >= qw + 15 - Wc);   // wave-uniform
        if (full) {
#pragma unroll
            for (int r = 0; r < 4; ++r) { p0[r] = exp2f(sc0[r]); p1[r] = exp2f(sc1[r]); }
        } else {
#pragma unroll
            for (int r = 0; r < 4; ++r) {
                int qi = qw + g * 4 + r;
                int sA = s0 + t, sB = sA + 16;
                p0[r] = (sA <= qi && sA >= qi - Wc) ? exp2f(sc0[r]) : 0.f;
                p1[r] = (sB <= qi && sB >= qi - Wc) ? exp2f(sc1[r]) : 0.f;
            }
        }
#pragma unroll
        for (int r = 0; r < 4; ++r) {
            lrow[r] += p0[r] + p1[r];
            pw[(g * 4 + r) * 16 + t] = pack2(p0[r], p1[r]);
        }
        asm volatile("s_waitcnt lgkmcnt(0)" ::: "memory");
        bf16x8 pf = *(const bf16x8*)((const __bf16*)pw + t * 32 + g * 8);
#pragma unroll
        for (int n = 0; n < 4; ++n) {
            const __bf16* vr = vb + (size_t)(n * 16 + t) * Tc + s0 + g * 8;
            oacc[n] = mfma_bf16(pf, *(const bf16x8*)vr, oacc[n]);
        }
    }
#pragma unroll
    for (int r = 0; r < 4; ++r) {
        float s = lrow[r];
#pragma unroll
        for (int m = 8; m; m >>= 1) s += __shfl_xor(s, m, 16);
        lrow[r] = 1.f / s;
    }
#pragma unroll
    for (int n = 0; n < 4; ++n)
#pragma unroll
        for (int r = 0; r < 4; ++r) {
            int qi = qw + g * 4 + r;
            ac[(size_t)(b * Tc + qi) * 1536 + h * 64 + n * 16 + t] =
                (__bf16)(oacc[n][r] * lrow[r]);
        }
}

// ---------------- GDN retrieval -> ac columns 768..1535, gmean-scaled ----------------
__global__ __launch_bounds__(256) void k_retr(
    const __bf16* __restrict__ qg, const __bf16* __restrict__ stateT,
    const float* __restrict__ gmean, __bf16* __restrict__ ac)
{
    int b = blockIdx.z, h = blockIdx.y;
    int w = threadIdx.x >> 6, lane = threadIdx.x & 63;
    int g = lane >> 4, t = lane & 15;
    int t0 = blockIdx.x * 64 + w * 16;
    const __bf16* qb = qg + (size_t)(b * Hc + h) * Tc * 64;
    const __bf16* sb = stateT + (size_t)(b * Hc + h) * 64 * 64;
    bf16x8 a0 = *(const bf16x8*)(qb + (size_t)(t0 + t) * 64 + g * 8);
    bf16x8 a1 = *(const bf16x8*)(qb + (size_t)(t0 + t) * 64 + 32 + g * 8);
#pragma unroll
    for (int n = 0; n < 4; ++n) {
        bf16x8 b0 = *(const bf16x8*)(sb + (n * 16 + t) * 64 + g * 8);
        bf16x8 b1 = *(const bf16x8*)(sb + (n * 16 + t) * 64 + 32 + g * 8);
        f32x4 acc = {};
        acc = mfma_bf16(a0, b0, acc);
        acc = mfma_bf16(a1, b1, acc);
#pragma unroll
        for (int r = 0; r < 4; ++r) {
            int ti = t0 + g * 4 + r;
            float gm = gmean[b * Tc + ti];
            ac[(size_t)(b * Tc + ti) * 1536 + 768 + h * 64 + n * 16 + t] =
                (__bf16)(acc[r] * gm);
        }
    }
}

// ---------------- host ----------------
extern "C" void kernel_launch(void* const* d_in, const int* in_sizes, int n_in,
                              void* d_out, int out_size, void* d_ws, size_t ws_size,
                              hipStream_t stream) {
    (void)in_sizes; (void)n_in; (void)out_size; (void)ws_size;
    const float* x     = (const float*)d_in[0];
    const float* gdn   = (const float*)d_in[1];
    const float* Wq    = (const float*)d_in[2];
    const float* Wk    = (const float*)d_in[3];
    const float* Wv    = (const float*)d_in[4];
    const float* Wo    = (const float*)d_in[5];
    const float* Wgq   = (const float*)d_in[6];
    const float* Wro   = (const float*)d_in[7];
    const float* Wg    = (const float*)d_in[8];
    const float* bg    = (const float*)d_in[9];
    const float* normw = (const float*)d_in[10];
    float* out = (float*)d_out;

    char* p = (char*)d_ws;
    auto alloc = [&](size_t bytes) -> char* {
        char* r = p; p += (bytes + 255) & ~(size_t)255; return r;
    };
    constexpr size_t NROW = (size_t)Bc * Tc;          // 4096
    __bf16* xnb    = (__bf16*)alloc(NROW * Dc * 2);
    __bf16* wTproj = (__bf16*)alloc((size_t)4 * Dc * Dc * 2);   // 3072 x 768
    __bf16* wTout  = (__bf16*)alloc((size_t)Dc * 1536 * 2);     // 768 x 1536
    __bf16* stT    = (__bf16*)alloc((size_t)Bc * Hc * 64 * 64 * 2);
    __bf16* qbuf   = (__bf16*)alloc(NROW * Dc * 2);
    __bf16* kbuf   = (__bf16*)alloc(NROW * Dc * 2);
    __bf16* qgbuf  = (__bf16*)alloc(NROW * Dc * 2);
    __bf16* vtbuf  = (__bf16*)alloc(NROW * Dc * 2);
    __bf16* ac     = (__bf16*)alloc(NROW * 1536 * 2);           // [local | retr]
    float*  gmean  = (float*)alloc(NROW * 4);

    k_prep_w<<<dim3(144, 6), 256, 0, stream>>>(Wq, Wk, Wv, Wgq, Wo, Wro, wTproj, wTout);
    k_prep_state<<<(Bc * Hc * 64 * 64) / 256, 256, 0, stream>>>(gdn, stT);
    k_rmsnorm<<<NROW, 256, 0, stream>>>(x, normw, xnb);
    k_gate<<<NROW / 4, 256, 0, stream>>>(xnb, Wg, bg, gmean);

    k_gemm<0><<<768, 256, 0, stream>>>(xnb, wTproj, nullptr, nullptr,
                                       qbuf, kbuf, vtbuf, qgbuf);
    k_attn<<<768, 256, 0, stream>>>(qbuf, kbuf, vtbuf, ac);
    k_retr<<<dim3(Tc / 64, Hc, Bc), 256, 0, stream>>>(qgbuf, stT, gmean, ac);
    k_gemm<1><<<384, 256, 0, stream>>>(ac, wTout, x, out,
                                       nullptr, nullptr, nullptr, nullptr);
}